// Round 7
// baseline (457.585 us; speedup 1.0000x reference)
//
#include <hip/hip_runtime.h>
#include <math.h>

#define D_IN  128
#define D_HID 256
#define D_OUT 256
#define NXCD  8

typedef __attribute__((ext_vector_type(8))) short bf16x8;
typedef __attribute__((ext_vector_type(4))) float f32x4;

__device__ __forceinline__ float bf2f(unsigned short u) {
    union { unsigned int i; float f; } v; v.i = ((unsigned int)u) << 16; return v.f;
}
__device__ __forceinline__ unsigned short f2bf(float f) {
    union { float f; unsigned int i; } v; v.f = f;
    unsigned int u = v.i;
    return (unsigned short)((u + 0x7FFFu + ((u >> 16) & 1u)) >> 16);
}
__device__ __forceinline__ float u2f(unsigned int u) {
    union { unsigned int i; float f; } v; v.i = u; return v.f;
}

#define GLOAD_LDS16(src, dst) \
    __builtin_amdgcn_global_load_lds((const __attribute__((address_space(1))) void*)(src), \
                                     (__attribute__((address_space(3))) void*)(dst), 16, 0, 0)

// ---------------------------------------------------------------- CSR build (XCD-partitioned hist/fill)
// blocks with (blockIdx.x & 7)==g land on XCD g (round-robin dispatch); group g owns rows
// [g*n/8,(g+1)*n/8) -> its deg/cursor/colout region stays in ONE L2 (R3: 107MB HBM write-amp fixed).
__global__ void hist_xcd(const int* __restrict__ r0, const int* __restrict__ r1, int E, int n,
                         int* __restrict__ d0, int* __restrict__ d1, int per) {
    const int* row = blockIdx.y ? r1 : r0;
    int* deg = blockIdx.y ? d1 : d0;
    const int g = blockIdx.x & (NXCD - 1);
    const int chunk = blockIdx.x >> 3;
    const int lo = g * (n >> 3);
    const int hi = (g == NXCD - 1) ? n : lo + (n >> 3);
    const int s = chunk * per, e = min(E, s + per);
    for (int i = s + (int)threadIdx.x; i < e; i += 256) {
        int r = row[i];
        if (r >= lo && r < hi) atomicAdd(&deg[r], 1);
    }
}

__global__ void fill_xcd(const int* __restrict__ r0, const int* __restrict__ c0,
                         const int* __restrict__ r1, const int* __restrict__ c1, int E, int n,
                         int* __restrict__ cu0, int* __restrict__ cu1,
                         int* __restrict__ o0, int* __restrict__ o1, int per) {
    const int* row = blockIdx.y ? r1 : r0;
    const int* colsrc = blockIdx.y ? c1 : c0;
    int* cursor = blockIdx.y ? cu1 : cu0;
    int* colout = blockIdx.y ? o1 : o0;
    const int g = blockIdx.x & (NXCD - 1);
    const int chunk = blockIdx.x >> 3;
    const int lo = g * (n >> 3);
    const int hi = (g == NXCD - 1) ? n : lo + (n >> 3);
    const int s = chunk * per, e = min(E, s + per);
    for (int i = s + (int)threadIdx.x; i < e; i += 256) {
        int r = row[i];
        if (r >= lo && r < hi) {
            int slot = atomicAdd(&cursor[r], 1);
            colout[slot] = colsrc[i];
        }
    }
}

__global__ void scan_partial2(const int* __restrict__ dg0, const int* __restrict__ dg1, int n,
                              int* __restrict__ p0, int* __restrict__ p1) {
    const int* deg = blockIdx.y ? dg1 : dg0;
    int* partial = blockIdx.y ? p1 : p0;
    __shared__ int sm[256];
    int i = blockIdx.x * 256 + threadIdx.x;
    sm[threadIdx.x] = (i < n) ? deg[i] : 0;
    __syncthreads();
    for (int off = 128; off > 0; off >>= 1) {
        if (threadIdx.x < off) sm[threadIdx.x] += sm[threadIdx.x + off];
        __syncthreads();
    }
    if (threadIdx.x == 0) partial[blockIdx.x] = sm[0];
}

__global__ void scan_top2(int* p0, int* p1, int nb) {
    int* partial = blockIdx.x ? p1 : p0;
    __shared__ int sm[256];
    int t = threadIdx.x;
    int orig = (t < nb) ? partial[t] : 0;
    sm[t] = orig;
    __syncthreads();
    for (int off = 1; off < 256; off <<= 1) {
        int v = (t >= off) ? sm[t - off] : 0;
        __syncthreads();
        sm[t] += v;
        __syncthreads();
    }
    if (t < nb) partial[t] = sm[t] - orig;   // exclusive prefix
}

__global__ void scan_final2(const int* __restrict__ dg0, const int* __restrict__ dg1,
                            const int* __restrict__ p0, const int* __restrict__ p1,
                            int n, int total,
                            int* __restrict__ rp0, int* __restrict__ rp1,
                            int* __restrict__ cu0, int* __restrict__ cu1) {
    const int* deg = blockIdx.y ? dg1 : dg0;
    const int* partial = blockIdx.y ? p1 : p0;
    int* rowptr = blockIdx.y ? rp1 : rp0;
    int* cursor = blockIdx.y ? cu1 : cu0;
    __shared__ int sm[256];
    int t = threadIdx.x;
    int i = blockIdx.x * 256 + t;
    int v = (i < n) ? deg[i] : 0;
    sm[t] = v;
    __syncthreads();
    for (int off = 1; off < 256; off <<= 1) {
        int u = (t >= off) ? sm[t - off] : 0;
        __syncthreads();
        sm[t] += u;
        __syncthreads();
    }
    int excl = sm[t] - v + partial[blockIdx.x];
    if (i < n) { rowptr[i] = excl; cursor[i] = excl; }
    if (i == n - 1) rowptr[n] = total;
}

// ---------------------------------------------------------------- conversions
__global__ void conv_x_kernel(const float* __restrict__ in, unsigned short* __restrict__ out, int n4) {
    int i = blockIdx.x * 256 + threadIdx.x;
    if (i < n4) {
        float4 v = ((const float4*)in)[i];
        ushort4 o;
        o.x = f2bf(v.x); o.y = f2bf(v.y); o.z = f2bf(v.z); o.w = f2bf(v.w);
        ((ushort4*)out)[i] = o;
    }
}

__global__ void conv_w_kernel(const float* w0, const float* w1, const float* w2, const float* w3,
                              const float* w4, const float* w5, const float* w6, const float* w7,
                              unsigned short* o0, unsigned short* o1, unsigned short* o2, unsigned short* o3,
                              unsigned short* o4, unsigned short* o5, unsigned short* o6, unsigned short* o7) {
    int m = blockIdx.y, c = blockIdx.x, k = threadIdx.x;
    const float* src; unsigned short* dst; int K;
    switch (m) {
        case 0: src = w0; dst = o0; K = 128; break;
        case 1: src = w1; dst = o1; K = 128; break;
        case 2: src = w2; dst = o2; K = 256; break;
        case 3: src = w3; dst = o3; K = 256; break;
        case 4: src = w4; dst = o4; K = 128; break;
        case 5: src = w5; dst = o5; K = 128; break;
        case 6: src = w6; dst = o6; K = 256; break;
        default: src = w7; dst = o7; K = 256; break;
    }
    if (k < K) dst[c * K + k] = f2bf(src[(size_t)k * 256 + c]);
}

// ---------------------------------------------------------------- aggregation body (one stream)
// RPW rows share one wave-instruction; clamped-index + weight-FMA keeps exec uniform.
template<int D>
__device__ __forceinline__ void agg_body(const unsigned short* __restrict__ x,
                                         const int* __restrict__ rowptr,
                                         const int* __restrict__ colidx,
                                         unsigned short* __restrict__ nei, int n, int blk) {
    constexpr int RPW = (D == 256) ? 2 : 4;        // rows per wave-instruction
    constexpr int LPR = 64 / RPW;                  // lanes per row (32 or 16)
    const int wave = threadIdx.x >> 6, lane = threadIdx.x & 63;
    const int node = blk * 4 + wave;
    if (node >= n) return;
    const int h = lane / LPR;                      // edge slot within group
    const int d = lane & (LPR - 1);                // 16B chunk within row

    const int s = rowptr[node], e = rowptr[node + 1];
    const float inv = 1.0f / ((float)(e - s) + 1e-12f);

    float acc[8] = {};
    if (s < e) {
        for (int j = s; j < e; j += 4 * RPW) {
            #pragma unroll
            for (int p = 0; p < 4; ++p) {
                int idx = j + p * RPW + h;
                float wgt = (idx < e) ? 1.0f : 0.0f;
                int c = colidx[idx < e ? idx : s];
                uint4 v = *(const uint4*)&x[(size_t)c * D + d * 8];
                acc[0] = fmaf(wgt, u2f(v.x << 16), acc[0]);
                acc[1] = fmaf(wgt, u2f(v.x & 0xFFFF0000u), acc[1]);
                acc[2] = fmaf(wgt, u2f(v.y << 16), acc[2]);
                acc[3] = fmaf(wgt, u2f(v.y & 0xFFFF0000u), acc[3]);
                acc[4] = fmaf(wgt, u2f(v.z << 16), acc[4]);
                acc[5] = fmaf(wgt, u2f(v.z & 0xFFFF0000u), acc[5]);
                acc[6] = fmaf(wgt, u2f(v.w << 16), acc[6]);
                acc[7] = fmaf(wgt, u2f(v.w & 0xFFFF0000u), acc[7]);
            }
        }
    }
    #pragma unroll
    for (int k = 0; k < 8; ++k) {
        if constexpr (RPW == 4) acc[k] += __shfl_xor(acc[k], 16);
        acc[k] += __shfl_xor(acc[k], 32);
    }
    if (h == 0) {
        uint4 o;
        o.x = (unsigned int)f2bf(acc[0] * inv) | ((unsigned int)f2bf(acc[1] * inv) << 16);
        o.y = (unsigned int)f2bf(acc[2] * inv) | ((unsigned int)f2bf(acc[3] * inv) << 16);
        o.z = (unsigned int)f2bf(acc[4] * inv) | ((unsigned int)f2bf(acc[5] * inv) << 16);
        o.w = (unsigned int)f2bf(acc[6] * inv) | ((unsigned int)f2bf(acc[7] * inv) << 16);
        *(uint4*)&nei[(size_t)node * D + d * 8] = o;
    }
}

// two-stream agg wrapper (layer 0: both streams share the xb table in L2/L3)
template<int D>
__global__ __launch_bounds__(256)
void agg3(const unsigned short* __restrict__ x0, const unsigned short* __restrict__ x1,
          const int* __restrict__ rp0, const int* __restrict__ ci0,
          const int* __restrict__ rp1, const int* __restrict__ ci1,
          unsigned short* __restrict__ n0, unsigned short* __restrict__ n1, int n) {
    agg_body<D>(blockIdx.y ? x1 : x0, blockIdx.y ? rp1 : rp0,
                blockIdx.y ? ci1 : ci0, blockIdx.y ? n1 : n0, n, blockIdx.x);
}

// ---------------------------------------------------------------- MFMA GEMM body (2-phase dbuf)
struct GemmArgs {
    const unsigned short* A0;
    const unsigned short* A1;
    const unsigned short* B0t;
    const unsigned short* B1t;
    const float* bias0;
    const float* bias1;
    void* out;
};

// C[128,128 tile] = epi( A0@W0 + A1@W1 + b0 + b1 )
// MODE 0: bf16 out = relu(h);  MODE 1: fp32 out = w*extra + (1-w)*relu(h)
template<int K, int MODE>
__device__ __forceinline__ void gemm_body(const GemmArgs& g, const unsigned short* __restrict__ extra,
                                          const float* __restrict__ alpha_p, int M,
                                          int row0, int col0,
                                          unsigned short (*Asm)[128 * 64],
                                          unsigned short (*Bsm)[128 * 64]) {
    constexpr int BK = 64;
    constexpr int NT = 2 * K / BK;                 // tiles across both operand pairs
    const int t = threadIdx.x;
    const int l = t & 63, w = t >> 6;
    const int wr = w >> 1, wc = w & 1;             // 2x2 wave grid, 64x64 per wave

    const int seg = l >> 3;                        // row within 8-row segment
    const int src_chunk = (l & 7) ^ seg;           // inverse-swizzled source chunk

    f32x4 acc[4][4] = {};

    auto STAGE = [&](int tt, int buf) {
        const int op = tt >= (K / BK);
        const int k0 = (tt - op * (K / BK)) * BK;
        const unsigned short* __restrict__ A  = op ? g.A1  : g.A0;
        const unsigned short* __restrict__ Bt = op ? g.B1t : g.B0t;
        #pragma unroll
        for (int i = 0; i < 4; ++i) {
            const int rbase = w * 32 + i * 8;
            int grow = row0 + rbase + seg; if (grow > M - 1) grow = M - 1;
            GLOAD_LDS16(A + (size_t)grow * K + k0 + src_chunk * 8, &Asm[buf][rbase * 64]);
            GLOAD_LDS16(Bt + (size_t)(col0 + rbase + seg) * K + k0 + src_chunk * 8, &Bsm[buf][rbase * 64]);
        }
    };

    STAGE(0, 0);
    #pragma unroll
    for (int tt = 0; tt < NT; ++tt) {
        const int cur = tt & 1;
        if (tt + 1 < NT) {
            STAGE(tt + 1, cur ^ 1);
            asm volatile("s_waitcnt vmcnt(8)" ::: "memory");   // current buf's 8 loads done
        } else {
            asm volatile("s_waitcnt vmcnt(0)" ::: "memory");
        }
        __builtin_amdgcn_s_barrier();
        #pragma unroll
        for (int kk = 0; kk < 2; ++kk) {
            bf16x8 af[4], bfr[4];
            #pragma unroll
            for (int m = 0; m < 4; ++m) {
                int r = wr * 64 + m * 16 + (l & 15);
                int ch = (kk * 4 + (l >> 4)) ^ (r & 7);
                af[m] = *(const bf16x8*)&Asm[cur][r * 64 + ch * 8];
            }
            #pragma unroll
            for (int n = 0; n < 4; ++n) {
                int r = wc * 64 + n * 16 + (l & 15);
                int ch = (kk * 4 + (l >> 4)) ^ (r & 7);
                bfr[n] = *(const bf16x8*)&Bsm[cur][r * 64 + ch * 8];
            }
            #pragma unroll
            for (int m = 0; m < 4; ++m)
                #pragma unroll
                for (int n = 0; n < 4; ++n)
                    acc[m][n] = __builtin_amdgcn_mfma_f32_16x16x32_bf16(af[m], bfr[n], acc[m][n], 0, 0, 0);
        }
        asm volatile("s_waitcnt lgkmcnt(0)" ::: "memory");
        __builtin_amdgcn_s_barrier();
    }

    float bsum[4];
    int cidx[4];
    #pragma unroll
    for (int n = 0; n < 4; ++n) {
        cidx[n] = col0 + wc * 64 + n * 16 + (l & 15);
        bsum[n] = g.bias0[cidx[n]] + g.bias1[cidx[n]];
    }
    float wmix = 0.f;
    if (MODE == 1) wmix = 1.0f / (1.0f + expf(-alpha_p[0]));

    #pragma unroll
    for (int m = 0; m < 4; ++m) {
        #pragma unroll
        for (int i = 0; i < 4; ++i) {
            int r = row0 + wr * 64 + m * 16 + (l >> 4) * 4 + i;
            if (r >= M) continue;
            #pragma unroll
            for (int n = 0; n < 4; ++n) {
                float h = acc[m][n][i] + bsum[n];
                float o = h > 0.f ? h : 0.f;
                if (MODE == 0) {
                    ((unsigned short*)g.out)[(size_t)r * 256 + cidx[n]] = f2bf(o);
                } else {
                    float ex = bf2f(extra[(size_t)r * 256 + cidx[n]]);
                    ((float*)g.out)[(size_t)r * 256 + cidx[n]] = wmix * ex + (1.f - wmix) * o;
                }
            }
        }
    }
}

template<int K, int MODE>
__global__ __launch_bounds__(256)
void gemm_mfma(GemmArgs g, const unsigned short* __restrict__ extra,
               const float* __restrict__ alpha_p, int M) {
    __shared__ unsigned short Asm[2][128 * 64];
    __shared__ unsigned short Bsm[2][128 * 64];
    gemm_body<K, MODE>(g, extra, alpha_p, M, blockIdx.x * 128, blockIdx.y * 128, Asm, Bsm);
}

// ---------------------------------------------------------------- heterogeneous overlap dispatch
// blocks [0, nGemm): one GEMM (row=(b>>1)*128, col=(b&1)*128); blocks [nGemm, ...): one agg stream.
// Gather-bound agg blocks saturate fabric while GEMM blocks run the matrix pipe — overlap without
// streams/events (graph-capture-safe, schedule-independent correctness).
template<int D, int K, int MODE>
__global__ __launch_bounds__(256)
void fused_ag(const unsigned short* __restrict__ ax, const int* __restrict__ arp,
              const int* __restrict__ aci, unsigned short* __restrict__ anei,
              GemmArgs g, const unsigned short* __restrict__ extra,
              const float* __restrict__ alpha_p, int M, int nGemm) {
    __shared__ unsigned short Asm[2][128 * 64];
    __shared__ unsigned short Bsm[2][128 * 64];
    const int b = blockIdx.x;
    if (b < nGemm) {
        gemm_body<K, MODE>(g, extra, alpha_p, M, (b >> 1) * 128, (b & 1) * 128, Asm, Bsm);
    } else {
        agg_body<D>(ax, arp, aci, anei, M, b - nGemm);
    }
}

// ---------------------------------------------------------------- launch
extern "C" void kernel_launch(void* const* d_in, const int* in_sizes, int n_in,
                              void* d_out, int out_size, void* d_ws, size_t ws_size,
                              hipStream_t stream) {
    const float* x       = (const float*)d_in[0];
    const float* alpha_p = (const float*)d_in[1];
    const float* s0_ws = (const float*)d_in[2],  *s0_bs = (const float*)d_in[3];
    const float* s0_wn = (const float*)d_in[4],  *s0_bn = (const float*)d_in[5];
    const float* s1_ws = (const float*)d_in[6],  *s1_bs = (const float*)d_in[7];
    const float* s1_wn = (const float*)d_in[8],  *s1_bn = (const float*)d_in[9];
    const float* a0_ws = (const float*)d_in[10], *a0_bs = (const float*)d_in[11];
    const float* a0_wn = (const float*)d_in[12], *a0_bn = (const float*)d_in[13];
    const float* a1_ws = (const float*)d_in[14], *a1_bs = (const float*)d_in[15];
    const float* a1_wn = (const float*)d_in[16], *a1_bn = (const float*)d_in[17];
    const int* es = (const int*)d_in[18];   // [2,E]: row then col
    const int* ea = (const int*)d_in[19];

    const int N = in_sizes[0] / D_IN;
    const int E = in_sizes[18] / 2;
    const int* es_row = es, *es_col = es + E;
    const int* ea_row = ea, *ea_col = ea + E;

    // workspace carve-up (256B aligned)
    char* wsb = (char*)d_ws;
    size_t off = 0;
    auto carve = [&](size_t bytes) -> char* {
        char* p = wsb + off;
        off += (bytes + 255) & ~(size_t)255;
        return p;
    };
    unsigned short* xb     = (unsigned short*)carve((size_t)N * 128 * 2);   // x bf16
    unsigned short* neib_s = (unsigned short*)carve((size_t)N * 256 * 2);
    unsigned short* neib_a = (unsigned short*)carve((size_t)N * 256 * 2);
    unsigned short* actb_a = (unsigned short*)carve((size_t)N * 256 * 2);   // ha0
    unsigned short* hb     = (unsigned short*)carve((size_t)N * 256 * 2);   // hs1
    unsigned short* actb_s = (unsigned short*)d_out;                        // hs0 (scratch; dead before final write)
    unsigned short* wt[8];
    const int wK[8] = {128, 128, 256, 256, 128, 128, 256, 256};
    for (int i = 0; i < 8; ++i) wt[i] = (unsigned short*)carve((size_t)wK[i] * 256 * 2);
    int* deg      = (int*)carve((size_t)2 * N * 4);
    int* deg_s    = deg, *deg_a = deg + N;
    int* rowptr_s = (int*)carve((size_t)(N + 1) * 4);
    int* rowptr_a = (int*)carve((size_t)(N + 1) * 4);
    int* cur_s    = (int*)carve((size_t)N * 4);
    int* cur_a    = (int*)carve((size_t)N * 4);
    int* col_s    = (int*)carve((size_t)E * 4);
    int* col_a    = (int*)carve((size_t)E * 4);
    int* part_s   = (int*)carve(256 * 4);
    int* part_a   = (int*)carve(256 * 4);

    const int NB = (N + 255) / 256;
    const int NCHUNK = 128;                       // edge chunks per XCD group
    const int PER = (E + NCHUNK - 1) / NCHUNK;

    // ---- conversions
    conv_x_kernel<<<(N * 128 / 4 + 255) / 256, 256, 0, stream>>>(x, xb, N * 128 / 4);
    conv_w_kernel<<<dim3(256, 8), 256, 0, stream>>>(s0_ws, s0_wn, s1_ws, s1_wn,
                                                    a0_ws, a0_wn, a1_ws, a1_wn,
                                                    wt[0], wt[1], wt[2], wt[3],
                                                    wt[4], wt[5], wt[6], wt[7]);

    // ---- CSR build (both edge sets, XCD-partitioned hist/fill)
    hipMemsetAsync(deg, 0, (size_t)2 * N * 4, stream);
    hist_xcd<<<dim3(NCHUNK * NXCD, 2), 256, 0, stream>>>(es_row, ea_row, E, N, deg_s, deg_a, PER);
    scan_partial2<<<dim3(NB, 2), 256, 0, stream>>>(deg_s, deg_a, N, part_s, part_a);
    scan_top2<<<2, 256, 0, stream>>>(part_s, part_a, NB);
    scan_final2<<<dim3(NB, 2), 256, 0, stream>>>(deg_s, deg_a, part_s, part_a, N, E,
                                                 rowptr_s, rowptr_a, cur_s, cur_a);
    fill_xcd<<<dim3(NCHUNK * NXCD, 2), 256, 0, stream>>>(es_row, es_col, ea_row, ea_col, E, N,
                                                         cur_s, cur_a, col_s, col_a, PER);

    const int AGB = (N + 3) / 4;
    const int GMB = (N + 127) / 128;
    const int NGEMM = GMB * 2;

    GemmArgs l0s = { xb, neib_s, wt[0], wt[1], s0_bs, s0_bn, actb_s };
    GemmArgs l0a = { xb, neib_a, wt[4], wt[5], a0_bs, a0_bn, actb_a };
    GemmArgs l1s = { actb_s, neib_s, wt[2], wt[3], s1_bs, s1_bn, hb };
    GemmArgs l1a = { actb_a, neib_a, wt[6], wt[7], a1_bs, a1_bn, d_out };

    // D2: layer-0 agg, both streams fused (shared xb table)
    agg3<128><<<dim3(AGB, 2), 256, 0, stream>>>(xb, xb, rowptr_s, col_s, rowptr_a, col_a,
                                                neib_s, neib_a, N);
    // D3: gemm L0 spatial
    gemm_mfma<128, 0><<<dim3(GMB, 2), 256, 0, stream>>>(l0s, nullptr, alpha_p, N);
    // D4: agg L1 spatial (reads actb_s from D3)  ∥  gemm L0 attr
    fused_ag<256, 128, 0><<<NGEMM + AGB, 256, 0, stream>>>(
        actb_s, rowptr_s, col_s, neib_s, l0a, nullptr, alpha_p, N, NGEMM);
    // D5: gemm L1 spatial (reads neib_s from D4)  ∥  agg L1 attr (reads actb_a from D4)
    fused_ag<256, 256, 0><<<NGEMM + AGB, 256, 0, stream>>>(
        actb_a, rowptr_a, col_a, neib_a, l1s, nullptr, alpha_p, N, NGEMM);
    // D6: gemm L1 attr + sigmoid mix with hs1
    gemm_mfma<256, 1><<<dim3(GMB, 2), 256, 0, stream>>>(l1a, hb, alpha_p, N);

    (void)n_in; (void)out_size; (void)ws_size;
}

// Round 8
// 413.239 us; speedup vs baseline: 1.1073x; 1.1073x over previous
//
#include <hip/hip_runtime.h>
#include <math.h>

#define D_IN  128
#define D_HID 256
#define D_OUT 256
#define NXCD  8

typedef __attribute__((ext_vector_type(8))) short bf16x8;
typedef __attribute__((ext_vector_type(4))) float f32x4;

__device__ __forceinline__ float bf2f(unsigned short u) {
    union { unsigned int i; float f; } v; v.i = ((unsigned int)u) << 16; return v.f;
}
__device__ __forceinline__ unsigned short f2bf(float f) {
    union { float f; unsigned int i; } v; v.f = f;
    unsigned int u = v.i;
    return (unsigned short)((u + 0x7FFFu + ((u >> 16) & 1u)) >> 16);
}
__device__ __forceinline__ float u2f(unsigned int u) {
    union { unsigned int i; float f; } v; v.i = u; return v.f;
}

#define GLOAD_LDS16(src, dst) \
    __builtin_amdgcn_global_load_lds((const __attribute__((address_space(1))) void*)(src), \
                                     (__attribute__((address_space(3))) void*)(dst), 16, 0, 0)

// ---------------------------------------------------------------- CSR build (XCD-partitioned hist/fill)
// blocks with (blockIdx.x & 7)==g land on XCD g (round-robin dispatch); group g owns rows
// [g*n/8,(g+1)*n/8) -> its deg/cursor/colout region stays in ONE L2 (R3->R4: fill write-amp fixed).
__global__ void hist_xcd(const int* __restrict__ r0, const int* __restrict__ r1, int E, int n,
                         int* __restrict__ d0, int* __restrict__ d1, int per) {
    const int* row = blockIdx.y ? r1 : r0;
    int* deg = blockIdx.y ? d1 : d0;
    const int g = blockIdx.x & (NXCD - 1);
    const int chunk = blockIdx.x >> 3;
    const int lo = g * (n >> 3);
    const int hi = (g == NXCD - 1) ? n : lo + (n >> 3);
    const int s = chunk * per, e = min(E, s + per);
    for (int i = s + (int)threadIdx.x; i < e; i += 256) {
        int r = row[i];
        if (r >= lo && r < hi) atomicAdd(&deg[r], 1);
    }
}

__global__ void fill_xcd(const int* __restrict__ r0, const int* __restrict__ c0,
                         const int* __restrict__ r1, const int* __restrict__ c1, int E, int n,
                         int* __restrict__ cu0, int* __restrict__ cu1,
                         int* __restrict__ o0, int* __restrict__ o1, int per) {
    const int* row = blockIdx.y ? r1 : r0;
    const int* colsrc = blockIdx.y ? c1 : c0;
    int* cursor = blockIdx.y ? cu1 : cu0;
    int* colout = blockIdx.y ? o1 : o0;
    const int g = blockIdx.x & (NXCD - 1);
    const int chunk = blockIdx.x >> 3;
    const int lo = g * (n >> 3);
    const int hi = (g == NXCD - 1) ? n : lo + (n >> 3);
    const int s = chunk * per, e = min(E, s + per);
    for (int i = s + (int)threadIdx.x; i < e; i += 256) {
        int r = row[i];
        if (r >= lo && r < hi) {
            int slot = atomicAdd(&cursor[r], 1);
            colout[slot] = colsrc[i];
        }
    }
}

__global__ void scan_partial2(const int* __restrict__ dg0, const int* __restrict__ dg1, int n,
                              int* __restrict__ p0, int* __restrict__ p1) {
    const int* deg = blockIdx.y ? dg1 : dg0;
    int* partial = blockIdx.y ? p1 : p0;
    __shared__ int sm[256];
    int i = blockIdx.x * 256 + threadIdx.x;
    sm[threadIdx.x] = (i < n) ? deg[i] : 0;
    __syncthreads();
    for (int off = 128; off > 0; off >>= 1) {
        if (threadIdx.x < off) sm[threadIdx.x] += sm[threadIdx.x + off];
        __syncthreads();
    }
    if (threadIdx.x == 0) partial[blockIdx.x] = sm[0];
}

__global__ void scan_top2(int* p0, int* p1, int nb) {
    int* partial = blockIdx.x ? p1 : p0;
    __shared__ int sm[256];
    int t = threadIdx.x;
    int orig = (t < nb) ? partial[t] : 0;
    sm[t] = orig;
    __syncthreads();
    for (int off = 1; off < 256; off <<= 1) {
        int v = (t >= off) ? sm[t - off] : 0;
        __syncthreads();
        sm[t] += v;
        __syncthreads();
    }
    if (t < nb) partial[t] = sm[t] - orig;   // exclusive prefix
}

__global__ void scan_final2(const int* __restrict__ dg0, const int* __restrict__ dg1,
                            const int* __restrict__ p0, const int* __restrict__ p1,
                            int n, int total,
                            int* __restrict__ rp0, int* __restrict__ rp1,
                            int* __restrict__ cu0, int* __restrict__ cu1) {
    const int* deg = blockIdx.y ? dg1 : dg0;
    const int* partial = blockIdx.y ? p1 : p0;
    int* rowptr = blockIdx.y ? rp1 : rp0;
    int* cursor = blockIdx.y ? cu1 : cu0;
    __shared__ int sm[256];
    int t = threadIdx.x;
    int i = blockIdx.x * 256 + t;
    int v = (i < n) ? deg[i] : 0;
    sm[t] = v;
    __syncthreads();
    for (int off = 1; off < 256; off <<= 1) {
        int u = (t >= off) ? sm[t - off] : 0;
        __syncthreads();
        sm[t] += u;
        __syncthreads();
    }
    int excl = sm[t] - v + partial[blockIdx.x];
    if (i < n) { rowptr[i] = excl; cursor[i] = excl; }
    if (i == n - 1) rowptr[n] = total;
}

// ---------------------------------------------------------------- conversions
__global__ void conv_x_kernel(const float* __restrict__ in, unsigned short* __restrict__ out, int n4) {
    int i = blockIdx.x * 256 + threadIdx.x;
    if (i < n4) {
        float4 v = ((const float4*)in)[i];
        ushort4 o;
        o.x = f2bf(v.x); o.y = f2bf(v.y); o.z = f2bf(v.z); o.w = f2bf(v.w);
        ((ushort4*)out)[i] = o;
    }
}

__global__ void conv_w_kernel(const float* w0, const float* w1, const float* w2, const float* w3,
                              const float* w4, const float* w5, const float* w6, const float* w7,
                              unsigned short* o0, unsigned short* o1, unsigned short* o2, unsigned short* o3,
                              unsigned short* o4, unsigned short* o5, unsigned short* o6, unsigned short* o7) {
    int m = blockIdx.y, c = blockIdx.x, k = threadIdx.x;
    const float* src; unsigned short* dst; int K;
    switch (m) {
        case 0: src = w0; dst = o0; K = 128; break;
        case 1: src = w1; dst = o1; K = 128; break;
        case 2: src = w2; dst = o2; K = 256; break;
        case 3: src = w3; dst = o3; K = 256; break;
        case 4: src = w4; dst = o4; K = 128; break;
        case 5: src = w5; dst = o5; K = 128; break;
        case 6: src = w6; dst = o6; K = 256; break;
        default: src = w7; dst = o7; K = 256; break;
    }
    if (k < K) dst[c * K + k] = f2bf(src[(size_t)k * 256 + c]);
}

// ---------------------------------------------------------------- aggregation body (one stream)
// RPW rows share one wave-instruction; clamped-index + weight-FMA keeps exec uniform.
template<int D>
__device__ __forceinline__ void agg_body(const unsigned short* __restrict__ x,
                                         const int* __restrict__ rowptr,
                                         const int* __restrict__ colidx,
                                         unsigned short* __restrict__ nei, int n, int blk) {
    constexpr int RPW = (D == 256) ? 2 : 4;        // rows per wave-instruction
    constexpr int LPR = 64 / RPW;                  // lanes per row (32 or 16)
    const int wave = threadIdx.x >> 6, lane = threadIdx.x & 63;
    const int node = blk * 4 + wave;
    if (node >= n) return;
    const int h = lane / LPR;                      // edge slot within group
    const int d = lane & (LPR - 1);                // 16B chunk within row

    const int s = rowptr[node], e = rowptr[node + 1];
    const float inv = 1.0f / ((float)(e - s) + 1e-12f);

    float acc[8] = {};
    if (s < e) {
        for (int j = s; j < e; j += 4 * RPW) {
            #pragma unroll
            for (int p = 0; p < 4; ++p) {
                int idx = j + p * RPW + h;
                float wgt = (idx < e) ? 1.0f : 0.0f;
                int c = colidx[idx < e ? idx : s];
                uint4 v = *(const uint4*)&x[(size_t)c * D + d * 8];
                acc[0] = fmaf(wgt, u2f(v.x << 16), acc[0]);
                acc[1] = fmaf(wgt, u2f(v.x & 0xFFFF0000u), acc[1]);
                acc[2] = fmaf(wgt, u2f(v.y << 16), acc[2]);
                acc[3] = fmaf(wgt, u2f(v.y & 0xFFFF0000u), acc[3]);
                acc[4] = fmaf(wgt, u2f(v.z << 16), acc[4]);
                acc[5] = fmaf(wgt, u2f(v.z & 0xFFFF0000u), acc[5]);
                acc[6] = fmaf(wgt, u2f(v.w << 16), acc[6]);
                acc[7] = fmaf(wgt, u2f(v.w & 0xFFFF0000u), acc[7]);
            }
        }
    }
    #pragma unroll
    for (int k = 0; k < 8; ++k) {
        if constexpr (RPW == 4) acc[k] += __shfl_xor(acc[k], 16);
        acc[k] += __shfl_xor(acc[k], 32);
    }
    if (h == 0) {
        uint4 o;
        o.x = (unsigned int)f2bf(acc[0] * inv) | ((unsigned int)f2bf(acc[1] * inv) << 16);
        o.y = (unsigned int)f2bf(acc[2] * inv) | ((unsigned int)f2bf(acc[3] * inv) << 16);
        o.z = (unsigned int)f2bf(acc[4] * inv) | ((unsigned int)f2bf(acc[5] * inv) << 16);
        o.w = (unsigned int)f2bf(acc[6] * inv) | ((unsigned int)f2bf(acc[7] * inv) << 16);
        *(uint4*)&nei[(size_t)node * D + d * 8] = o;
    }
}

// two-stream agg wrapper (layer 0: both streams share the xb table, no pinning gain possible)
template<int D>
__global__ __launch_bounds__(256)
void agg3(const unsigned short* __restrict__ x0, const unsigned short* __restrict__ x1,
          const int* __restrict__ rp0, const int* __restrict__ ci0,
          const int* __restrict__ rp1, const int* __restrict__ ci1,
          unsigned short* __restrict__ n0, unsigned short* __restrict__ n1, int n) {
    agg_body<D>(blockIdx.y ? x1 : x0, blockIdx.y ? rp1 : rp0,
                blockIdx.y ? ci1 : ci0, blockIdx.y ? n1 : n0, n, blockIdx.x);
}

// layer-1 agg with stream->half-chip pinning: XCD slots 0-3 (blockIdx.x&7 < 4) process stream 0,
// slots 4-7 stream 1. Each 25.6MB table is then replicated into only 4 XCDs' L2-miss streams
// (~200K gathers/XCD over 50K lines = 98% coverage) instead of 8x86% -> fabric fetch ~350->~210MB.
// Correctness is independent of the blockIdx->XCD mapping (any block anywhere computes the same).
template<int D>
__global__ __launch_bounds__(256)
void agg_half(const unsigned short* __restrict__ x0, const unsigned short* __restrict__ x1,
              const int* __restrict__ rp0, const int* __restrict__ ci0,
              const int* __restrict__ rp1, const int* __restrict__ ci1,
              unsigned short* __restrict__ n0, unsigned short* __restrict__ n1, int n) {
    const int g = blockIdx.x & 7;                  // XCD slot
    const int strm = g >> 2;                       // 0: spatial (slots 0-3), 1: attr (slots 4-7)
    const int blk = ((int)blockIdx.x >> 3) * 4 + (g & 3);
    agg_body<D>(strm ? x1 : x0, strm ? rp1 : rp0,
                strm ? ci1 : ci0, strm ? n1 : n0, n, blk);
}

// ---------------------------------------------------------------- MFMA GEMM (2-phase dbuf pipeline)
struct GemmArgs {
    const unsigned short* A0;
    const unsigned short* A1;
    const unsigned short* B0t;
    const unsigned short* B1t;
    const float* bias0;
    const float* bias1;
    void* out;
};

// C[M,256] = epi( A0@W0 + A1@W1 + b0 + b1 ); blockIdx.z selects g0/g1
// MODE 0: bf16 out = relu(h);  MODE 1: fp32 out = w*extra + (1-w)*relu(h)
template<int K, int MODE>
__global__ __launch_bounds__(256)
void gemm_mfma(GemmArgs g0, GemmArgs g1, const unsigned short* __restrict__ extra,
               const float* __restrict__ alpha_p, int M) {
    constexpr int BK = 64;
    constexpr int NT = 2 * K / BK;                 // tiles across both operand pairs
    __shared__ unsigned short Asm[2][128 * BK];    // [128][64] row-major, 16B chunks XOR-swizzled
    __shared__ unsigned short Bsm[2][128 * BK];
    const GemmArgs g = blockIdx.z ? g1 : g0;
    const int t = threadIdx.x;
    const int l = t & 63, w = t >> 6;
    const int wr = w >> 1, wc = w & 1;             // 2x2 wave grid, 64x64 per wave
    const int row0 = blockIdx.x * 128;
    const int col0 = blockIdx.y * 128;

    const int seg = l >> 3;                        // row within 8-row segment
    const int src_chunk = (l & 7) ^ seg;           // inverse-swizzled source chunk

    f32x4 acc[4][4] = {};

    auto STAGE = [&](int tt, int buf) {
        const int op = tt >= (K / BK);
        const int k0 = (tt - op * (K / BK)) * BK;
        const unsigned short* __restrict__ A  = op ? g.A1  : g.A0;
        const unsigned short* __restrict__ Bt = op ? g.B1t : g.B0t;
        #pragma unroll
        for (int i = 0; i < 4; ++i) {
            const int rbase = w * 32 + i * 8;
            int grow = row0 + rbase + seg; if (grow > M - 1) grow = M - 1;
            GLOAD_LDS16(A + (size_t)grow * K + k0 + src_chunk * 8, &Asm[buf][rbase * 64]);
            GLOAD_LDS16(Bt + (size_t)(col0 + rbase + seg) * K + k0 + src_chunk * 8, &Bsm[buf][rbase * 64]);
        }
    };

    STAGE(0, 0);
    #pragma unroll
    for (int tt = 0; tt < NT; ++tt) {
        const int cur = tt & 1;
        if (tt + 1 < NT) {
            STAGE(tt + 1, cur ^ 1);
            asm volatile("s_waitcnt vmcnt(8)" ::: "memory");   // current buf's 8 loads done
        } else {
            asm volatile("s_waitcnt vmcnt(0)" ::: "memory");
        }
        __builtin_amdgcn_s_barrier();
        #pragma unroll
        for (int kk = 0; kk < 2; ++kk) {
            bf16x8 af[4], bfr[4];
            #pragma unroll
            for (int m = 0; m < 4; ++m) {
                int r = wr * 64 + m * 16 + (l & 15);
                int ch = (kk * 4 + (l >> 4)) ^ (r & 7);
                af[m] = *(const bf16x8*)&Asm[cur][r * 64 + ch * 8];
            }
            #pragma unroll
            for (int n = 0; n < 4; ++n) {
                int r = wc * 64 + n * 16 + (l & 15);
                int ch = (kk * 4 + (l >> 4)) ^ (r & 7);
                bfr[n] = *(const bf16x8*)&Bsm[cur][r * 64 + ch * 8];
            }
            #pragma unroll
            for (int m = 0; m < 4; ++m)
                #pragma unroll
                for (int n = 0; n < 4; ++n)
                    acc[m][n] = __builtin_amdgcn_mfma_f32_16x16x32_bf16(af[m], bfr[n], acc[m][n], 0, 0, 0);
        }
        asm volatile("s_waitcnt lgkmcnt(0)" ::: "memory");
        __builtin_amdgcn_s_barrier();
    }

    // ---- epilogue: row = row0+wr*64+m*16+(l>>4)*4+i, col = col0+wc*64+n*16+(l&15)
    float bsum[4];
    int cidx[4];
    #pragma unroll
    for (int n = 0; n < 4; ++n) {
        cidx[n] = col0 + wc * 64 + n * 16 + (l & 15);
        bsum[n] = g.bias0[cidx[n]] + g.bias1[cidx[n]];
    }
    float wmix = 0.f;
    if (MODE == 1) wmix = 1.0f / (1.0f + expf(-alpha_p[0]));

    #pragma unroll
    for (int m = 0; m < 4; ++m) {
        #pragma unroll
        for (int i = 0; i < 4; ++i) {
            int r = row0 + wr * 64 + m * 16 + (l >> 4) * 4 + i;
            if (r >= M) continue;
            #pragma unroll
            for (int n = 0; n < 4; ++n) {
                float h = acc[m][n][i] + bsum[n];
                float o = h > 0.f ? h : 0.f;
                if (MODE == 0) {
                    ((unsigned short*)g.out)[(size_t)r * 256 + cidx[n]] = f2bf(o);
                } else {
                    float ex = bf2f(extra[(size_t)r * 256 + cidx[n]]);
                    ((float*)g.out)[(size_t)r * 256 + cidx[n]] = wmix * ex + (1.f - wmix) * o;
                }
            }
        }
    }
}

// ---------------------------------------------------------------- launch
extern "C" void kernel_launch(void* const* d_in, const int* in_sizes, int n_in,
                              void* d_out, int out_size, void* d_ws, size_t ws_size,
                              hipStream_t stream) {
    const float* x       = (const float*)d_in[0];
    const float* alpha_p = (const float*)d_in[1];
    const float* s0_ws = (const float*)d_in[2],  *s0_bs = (const float*)d_in[3];
    const float* s0_wn = (const float*)d_in[4],  *s0_bn = (const float*)d_in[5];
    const float* s1_ws = (const float*)d_in[6],  *s1_bs = (const float*)d_in[7];
    const float* s1_wn = (const float*)d_in[8],  *s1_bn = (const float*)d_in[9];
    const float* a0_ws = (const float*)d_in[10], *a0_bs = (const float*)d_in[11];
    const float* a0_wn = (const float*)d_in[12], *a0_bn = (const float*)d_in[13];
    const float* a1_ws = (const float*)d_in[14], *a1_bs = (const float*)d_in[15];
    const float* a1_wn = (const float*)d_in[16], *a1_bn = (const float*)d_in[17];
    const int* es = (const int*)d_in[18];   // [2,E]: row then col
    const int* ea = (const int*)d_in[19];

    const int N = in_sizes[0] / D_IN;
    const int E = in_sizes[18] / 2;
    const int* es_row = es, *es_col = es + E;
    const int* ea_row = ea, *ea_col = ea + E;

    // workspace carve-up (256B aligned)
    char* wsb = (char*)d_ws;
    size_t off = 0;
    auto carve = [&](size_t bytes) -> char* {
        char* p = wsb + off;
        off += (bytes + 255) & ~(size_t)255;
        return p;
    };
    unsigned short* xb     = (unsigned short*)carve((size_t)N * 128 * 2);   // x bf16
    unsigned short* neib_s = (unsigned short*)carve((size_t)N * 256 * 2);
    unsigned short* neib_a = (unsigned short*)carve((size_t)N * 256 * 2);
    unsigned short* actb_a = (unsigned short*)carve((size_t)N * 256 * 2);   // ha0
    unsigned short* hb     = (unsigned short*)carve((size_t)N * 256 * 2);   // hs1
    unsigned short* actb_s = (unsigned short*)d_out;                        // hs0 (scratch; dead before final write)
    unsigned short* wt[8];
    const int wK[8] = {128, 128, 256, 256, 128, 128, 256, 256};
    for (int i = 0; i < 8; ++i) wt[i] = (unsigned short*)carve((size_t)wK[i] * 256 * 2);
    int* deg      = (int*)carve((size_t)2 * N * 4);
    int* deg_s    = deg, *deg_a = deg + N;
    int* rowptr_s = (int*)carve((size_t)(N + 1) * 4);
    int* rowptr_a = (int*)carve((size_t)(N + 1) * 4);
    int* cur_s    = (int*)carve((size_t)N * 4);
    int* cur_a    = (int*)carve((size_t)N * 4);
    int* col_s    = (int*)carve((size_t)E * 4);
    int* col_a    = (int*)carve((size_t)E * 4);
    int* part_s   = (int*)carve(256 * 4);
    int* part_a   = (int*)carve(256 * 4);

    const int NB = (N + 255) / 256;
    const int NCHUNK = 128;                       // edge chunks per XCD group
    const int PER = (E + NCHUNK - 1) / NCHUNK;

    // ---- conversions
    conv_x_kernel<<<(N * 128 / 4 + 255) / 256, 256, 0, stream>>>(x, xb, N * 128 / 4);
    conv_w_kernel<<<dim3(256, 8), 256, 0, stream>>>(s0_ws, s0_wn, s1_ws, s1_wn,
                                                    a0_ws, a0_wn, a1_ws, a1_wn,
                                                    wt[0], wt[1], wt[2], wt[3],
                                                    wt[4], wt[5], wt[6], wt[7]);

    // ---- CSR build (both edge sets, XCD-partitioned hist/fill)
    hipMemsetAsync(deg, 0, (size_t)2 * N * 4, stream);
    hist_xcd<<<dim3(NCHUNK * NXCD, 2), 256, 0, stream>>>(es_row, ea_row, E, N, deg_s, deg_a, PER);
    scan_partial2<<<dim3(NB, 2), 256, 0, stream>>>(deg_s, deg_a, N, part_s, part_a);
    scan_top2<<<2, 256, 0, stream>>>(part_s, part_a, NB);
    scan_final2<<<dim3(NB, 2), 256, 0, stream>>>(deg_s, deg_a, part_s, part_a, N, E,
                                                 rowptr_s, rowptr_a, cur_s, cur_a);
    fill_xcd<<<dim3(NCHUNK * NXCD, 2), 256, 0, stream>>>(es_row, es_col, ea_row, ea_col, E, N,
                                                         cur_s, cur_a, col_s, col_a, PER);

    const int AGB = (N + 3) / 4;
    const int GMB = (N + 127) / 128;

    GemmArgs l0s = { xb, neib_s, wt[0], wt[1], s0_bs, s0_bn, actb_s };
    GemmArgs l0a = { xb, neib_a, wt[4], wt[5], a0_bs, a0_bn, actb_a };
    GemmArgs l1s = { actb_s, neib_s, wt[2], wt[3], s1_bs, s1_bn, hb };
    GemmArgs l1a = { actb_a, neib_a, wt[6], wt[7], a1_bs, a1_bn, d_out };

    // ---- layer 0 (both streams fused; shared xb table)
    agg3<128><<<dim3(AGB, 2), 256, 0, stream>>>(xb, xb, rowptr_s, col_s, rowptr_a, col_a,
                                                neib_s, neib_a, N);
    gemm_mfma<128, 0><<<dim3(GMB, 2, 2), 256, 0, stream>>>(l0s, l0a, nullptr, alpha_p, N);

    // ---- layer 1 agg: stream->half-chip pinned (distinct tables -> 4-XCD replication each)
    agg_half<256><<<8 * ((AGB + 3) / 4), 256, 0, stream>>>(
        actb_s, actb_a, rowptr_s, col_s, rowptr_a, col_a, neib_s, neib_a, N);
    gemm_mfma<256, 0><<<dim3(GMB, 2, 1), 256, 0, stream>>>(l1s, l1s, nullptr, alpha_p, N);
    gemm_mfma<256, 1><<<dim3(GMB, 2, 1), 256, 0, stream>>>(l1a, l1a, hb, alpha_p, N);

    (void)n_in; (void)out_size; (void)ws_size;
}